// Round 5
// baseline (128.026 us; speedup 1.0000x reference)
//
#include <hip/hip_runtime.h>

// LCN spiking net, round 10: transpose-first, all big layers in the proven
// transposed-gather pattern.
//  - r9 post-mortem: GATHER25 won (-3.5us). Remaining ~39us controllable:
//    l0_stage is the outlier — 57.6KB LDS forces 1 block (4 waves)/CU, no
//    latency hiding, 8x-amplified x stage. Every other big layer uses
//    layer_t_k (full occupancy, 1 L2-hot 128B line per half-wave gather,
//    broadcast weights).
//  - Fix: 32x14400 tile-transpose of the last timestep (1.84MB, LDS 32x33,
//    coalesced both sides, ~1-2us) -> layer 0 becomes layer_t_k too
//    (900 blocks, ~14 waves/CU, xT L2-resident).
//  - Also: int4/float4 knn/w loads in layer_t_k/_rm (50 -> 13 VMEM issues
//    per output).
//  - Nodes: xpose, l0t, l1, l2(row-major out), tail34fc. No memset node.

#define ROWS 32
#define TSTEPS 20
#define D0 14400
#define D1 7200
#define D2 3600
#define D3 1800
#define D4 900
#define D5 450
#define KNB 25

// 25-element gather from an LDS row, 16B index/weight loads.
#define GATHER25(acc, kp, wp, SRC)                                  \
    {                                                               \
        _Pragma("unroll")                                           \
        for (int k = 0; k < 24; k += 4) {                           \
            int4   ki; __builtin_memcpy(&ki, (kp) + k, 16);         \
            float4 wi; __builtin_memcpy(&wi, (wp) + k, 16);         \
            acc += SRC(ki.x) * wi.x + SRC(ki.y) * wi.y              \
                 + SRC(ki.z) * wi.z + SRC(ki.w) * wi.w;             \
        }                                                           \
        acc += SRC((kp)[24]) * (wp)[24];                            \
    }

// 25-element transposed-layout gather: pin[(idx<<5)+r], 16B kn/w loads.
#define GATHER25_T(acc, kp, wp, pin, r)                             \
    {                                                               \
        _Pragma("unroll")                                           \
        for (int k = 0; k < 24; k += 4) {                           \
            int4   ki; __builtin_memcpy(&ki, (kp) + k, 16);         \
            float4 wi; __builtin_memcpy(&wi, (wp) + k, 16);         \
            acc += (pin)[(ki.x << 5) + (r)] * wi.x                  \
                 + (pin)[(ki.y << 5) + (r)] * wi.y                  \
                 + (pin)[(ki.z << 5) + (r)] * wi.z                  \
                 + (pin)[(ki.w << 5) + (r)] * wi.w;                 \
        }                                                           \
        acc += (pin)[((kp)[24] << 5) + (r)] * (wp)[24];             \
    }

// K0: transpose x[:, T-1, :] (32 x 14400) -> xT[d][r] (14400 x 32).
// 450 blocks x 256 threads, one 32x32 tile each, LDS padded 32x33.
__global__ __launch_bounds__(256)
void xpose(const float* __restrict__ x, float* __restrict__ xT)
{
    __shared__ float t[32][33];
    const int d0 = blockIdx.x << 5;
    const int c  = threadIdx.x & 31;
    const int q  = threadIdx.x >> 5;   // 0..7

#pragma unroll
    for (int i = 0; i < 4; ++i) {
        const int r = q + (i << 3);
        t[c][r] = x[(size_t)r * (TSTEPS * D0) + (size_t)(TSTEPS - 1) * D0 + d0 + c];
    }
    __syncthreads();
#pragma unroll
    for (int i = 0; i < 4; ++i) {
        const int dd = q + (i << 3);
        xT[((d0 + dd) << 5) + c] = t[dd][c];
    }
}

// Transposed gather -> transposed write.
// pout[j][r] = b[j] + sum_k pin[knn[j][k]][r]*w[j][k]
// Wave = 2 outputs x 32 rows; gather = 1 contiguous 128B line per half-wave.
__global__ __launch_bounds__(256)
void layer_t_k(const float* __restrict__ pin, float* __restrict__ pout,
               const float* __restrict__ w, const float* __restrict__ bvec,
               const int* __restrict__ knn, int npairs)
{
    const int lane = threadIdx.x & 63;
    const int r  = lane & 31;
    const int jj = lane >> 5;
    const int nw = gridDim.x << 2;
#pragma unroll 1
    for (int jp = (blockIdx.x << 2) + (threadIdx.x >> 6); jp < npairs; jp += nw) {
        const int j = (jp << 1) + jj;
        const int*   kn = knn + j * KNB;
        const float* ww = w   + j * KNB;
        float acc = bvec[j];
        GATHER25_T(acc, kn, ww, pin, r)
        pout[(j << 5) + r] = acc;
    }
}

// Transposed gather -> ROW-major write (producer for the tail's coalesced stage).
__global__ __launch_bounds__(256)
void layer_t_k_rm(const float* __restrict__ pin, float* __restrict__ pout,
                  const float* __restrict__ w, const float* __restrict__ bvec,
                  const int* __restrict__ knn, int npairs, int dout)
{
    const int lane = threadIdx.x & 63;
    const int r  = lane & 31;
    const int jj = lane >> 5;
    const int nw = gridDim.x << 2;
#pragma unroll 1
    for (int jp = (blockIdx.x << 2) + (threadIdx.x >> 6); jp < npairs; jp += nw) {
        const int j = (jp << 1) + jj;
        const int*   kn = knn + j * KNB;
        const float* ww = w   + j * KNB;
        float acc = bvec[j];
        GATHER25_T(acc, kn, ww, pin, r)
        pout[r * dout + j] = acc;   // row-major scatter (spread full-chip)
    }
}

// Tail: layers 3-4 + FC, one block per row (32 x 1024).
__global__ __launch_bounds__(1024)
void tail34fc(const float* __restrict__ h3,
              const float* __restrict__ w3, const float* __restrict__ b3, const int* __restrict__ n3,
              const float* __restrict__ w4, const float* __restrict__ b4, const int* __restrict__ n4,
              const float* __restrict__ Wfc, const float* __restrict__ bfc,
              float* __restrict__ out)
{
    __shared__ float s3[D3];  // 7.2 KB
    __shared__ float s4[D4];  // 3.6 KB
    __shared__ float s5[D5];  // 1.8 KB
    __shared__ float red[2];

    const int r   = blockIdx.x;
    const int tid = threadIdx.x;

    if (tid < D3 / 4) {
        reinterpret_cast<float4*>(s3)[tid] =
            reinterpret_cast<const float4*>(h3 + (size_t)r * D3)[tid];
    }
    if (tid == 0) { red[0] = bfc[0]; red[1] = bfc[1]; }
    __syncthreads();

    // layer 3: 1800 -> 900
    if (tid < D4) {
        const int*   kn = n3 + tid * KNB;
        const float* ww = w3 + tid * KNB;
        float acc = b3[tid];
#define S3_SRC(idx) s3[idx]
        GATHER25(acc, kn, ww, S3_SRC)
#undef S3_SRC
        s4[tid] = acc;
    }
    __syncthreads();

    // layer 4: 900 -> 450
    if (tid < D5) {
        const int*   kn = n4 + tid * KNB;
        const float* ww = w4 + tid * KNB;
        float acc = b4[tid];
#define S4_SRC(idx) s4[idx]
        GATHER25(acc, kn, ww, S4_SRC)
#undef S4_SRC
        s5[tid] = acc;
    }
    __syncthreads();

    // FC: 450 -> 2
    float c0 = 0.0f, c1 = 0.0f;
    if (tid < D5) {
        const float v = s5[tid];
        c0 = v * Wfc[2 * tid + 0];
        c1 = v * Wfc[2 * tid + 1];
    }
#pragma unroll
    for (int off = 32; off > 0; off >>= 1) {
        c0 += __shfl_down(c0, off);
        c1 += __shfl_down(c1, off);
    }
    if ((tid & 63) == 0 && tid < D5) {
        atomicAdd(&red[0], c0);
        atomicAdd(&red[1], c1);
    }
    __syncthreads();
    if (tid < 2)
        out[2 * r + tid] = red[tid];
}

extern "C" void kernel_launch(void* const* d_in, const int* in_sizes, int n_in,
                              void* d_out, int out_size, void* d_ws, size_t ws_size,
                              hipStream_t stream)
{
    const float* x    = (const float*)d_in[0];
    const float* w0   = (const float*)d_in[1];
    const float* b0   = (const float*)d_in[2];
    const int*   knn0 = (const int*)  d_in[3];
    const float* w1   = (const float*)d_in[4];
    const float* b1   = (const float*)d_in[5];
    const int*   knn1 = (const int*)  d_in[6];
    const float* w2   = (const float*)d_in[7];
    const float* b2   = (const float*)d_in[8];
    const int*   knn2 = (const int*)  d_in[9];
    const float* w3   = (const float*)d_in[10];
    const float* b3   = (const float*)d_in[11];
    const int*   knn3 = (const int*)  d_in[12];
    const float* w4   = (const float*)d_in[13];
    const float* b4   = (const float*)d_in[14];
    const int*   knn4 = (const int*)  d_in[15];
    const float* Wfc  = (const float*)d_in[16];
    const float* bfc  = (const float*)d_in[17];
    float* out = (float*)d_out;

    // ws: xT[D0][32] | h1t[D1][32] | h2t[D2][32] | h3[32][D3] row-major
    float* xT  = (float*)d_ws;
    float* h1t = xT  + (size_t)D0 * ROWS;
    float* h2t = h1t + (size_t)D1 * ROWS;
    float* h3  = h2t + (size_t)D2 * ROWS;

    // transpose x last step: 450 tiles of 32x32
    xpose<<<dim3(D0 / 32), dim3(256), 0, stream>>>(x, xT);

    // layer 0: xT -> h1t (3600 pairs, full chip)
    layer_t_k<<<dim3(900), dim3(256), 0, stream>>>(xT, h1t, w0, b0, knn0, D1 / 2);

    // layer 1: h1t -> h2t (1800 pairs)
    layer_t_k<<<dim3(450), dim3(256), 0, stream>>>(h1t, h2t, w1, b1, knn1, D2 / 2);

    // layer 2: h2t -> h3 row-major (900 pairs)
    layer_t_k_rm<<<dim3(225), dim3(256), 0, stream>>>(h2t, h3, w2, b2, knn2, D3 / 2, D3);

    // layers 3-4 + FC: one block per row, direct write (no memset)
    tail34fc<<<dim3(ROWS), dim3(1024), 0, stream>>>(
        h3,
        w3, b3, knn3,
        w4, b4, knn4,
        Wfc, bfc, out);
}

// Round 6
// 127.835 us; speedup vs baseline: 1.0015x; 1.0015x over previous
//
#include <hip/hip_runtime.h>

// LCN spiking net, round 11: r9 structure + l0 occupancy fix.
//  - r10 post-mortem: +1 node (xpose) costs ~2us fixed; body swap was ~even
//    -> regression. Node count stays at 4; attack latency hiding instead.
//  - l0_stage was the occupancy hole: 256 threads + 57.6KB LDS = 4 waves/CU,
//    52 VMEM + 25 LDS reads per thread fully latency-exposed. Widen to 1024
//    threads: 16 waves/CU, stage = 3.5 coalesced float4 iters, gather = ONE
//    iteration (j = j0 + tid, tid < 900). Same grid, same traffic.
//  - Everything else identical to the 126.1us r9 kernel: l1 (transposed),
//    l2 (row-major handoff), tail34fc (l3+l4+FC per row, direct out write).

#define ROWS 32
#define TSTEPS 20
#define D0 14400
#define D1 7200
#define D2 3600
#define D3 1800
#define D4 900
#define D5 450
#define KNB 25

// 25-element gather from an LDS row, 16B index/weight loads.
#define GATHER25(acc, kp, wp, SRC)                                  \
    {                                                               \
        _Pragma("unroll")                                           \
        for (int k = 0; k < 24; k += 4) {                           \
            int4   ki; __builtin_memcpy(&ki, (kp) + k, 16);         \
            float4 wi; __builtin_memcpy(&wi, (wp) + k, 16);         \
            acc += SRC(ki.x) * wi.x + SRC(ki.y) * wi.y              \
                 + SRC(ki.z) * wi.z + SRC(ki.w) * wi.w;             \
        }                                                           \
        acc += SRC((kp)[24]) * (wp)[24];                            \
    }

// 25-element transposed-layout gather: pin[(idx<<5)+r], 16B kn/w loads.
#define GATHER25_T(acc, kp, wp, pin, r)                             \
    {                                                               \
        _Pragma("unroll")                                           \
        for (int k = 0; k < 24; k += 4) {                           \
            int4   ki; __builtin_memcpy(&ki, (kp) + k, 16);         \
            float4 wi; __builtin_memcpy(&wi, (wp) + k, 16);         \
            acc += (pin)[(ki.x << 5) + (r)] * wi.x                  \
                 + (pin)[(ki.y << 5) + (r)] * wi.y                  \
                 + (pin)[(ki.z << 5) + (r)] * wi.z                  \
                 + (pin)[(ki.w << 5) + (r)] * wi.w;                 \
        }                                                           \
        acc += (pin)[((kp)[24] << 5) + (r)] * (wp)[24];             \
    }

// K1: layer 0. Grid (8, ROWS), block 1024 (16 waves/CU). Stage x row in LDS
// (3.5 coalesced float4 iters), one gather iteration per thread, write h1t
// transposed.
__global__ __launch_bounds__(1024)
void l0_stage(const float* __restrict__ x, float* __restrict__ h1t,
              const float* __restrict__ w, const float* __restrict__ bvec,
              const int* __restrict__ knn)
{
    __shared__ float s[D0];   // 57.6 KB
    const int r = blockIdx.y;
    const float* xrow = x + ((size_t)r * TSTEPS + (TSTEPS - 1)) * (size_t)D0;

    const float4* src = reinterpret_cast<const float4*>(xrow);
    float4* dst = reinterpret_cast<float4*>(s);
#pragma unroll 1
    for (int i = threadIdx.x; i < D0 / 4; i += 1024)
        dst[i] = src[i];
    __syncthreads();

    const int j = blockIdx.x * 900 + threadIdx.x;
    if (threadIdx.x < 900) {
        const int*   kn = knn + j * KNB;
        const float* ww = w   + j * KNB;
        float acc = bvec[j];
#define LDS_SRC(idx) s[idx]
        GATHER25(acc, kn, ww, LDS_SRC)
#undef LDS_SRC
        h1t[(j << 5) + r] = acc;   // transposed write
    }
}

// K2: transposed gather -> transposed write.
// pout[j][r] = b[j] + sum_k pin[knn[j][k]][r]*w[j][k]
// Wave = 2 outputs x 32 rows; gather = 1 contiguous 128B line per half-wave.
__global__ __launch_bounds__(256)
void layer_t_k(const float* __restrict__ pin, float* __restrict__ pout,
               const float* __restrict__ w, const float* __restrict__ bvec,
               const int* __restrict__ knn, int npairs)
{
    const int lane = threadIdx.x & 63;
    const int r  = lane & 31;
    const int jj = lane >> 5;
    const int nw = gridDim.x << 2;
#pragma unroll 1
    for (int jp = (blockIdx.x << 2) + (threadIdx.x >> 6); jp < npairs; jp += nw) {
        const int j = (jp << 1) + jj;
        const int*   kn = knn + j * KNB;
        const float* ww = w   + j * KNB;
        float acc = bvec[j];
        GATHER25_T(acc, kn, ww, pin, r)
        pout[(j << 5) + r] = acc;
    }
}

// K3: transposed gather -> ROW-major write (for the tail's coalesced stage).
__global__ __launch_bounds__(256)
void layer_t_k_rm(const float* __restrict__ pin, float* __restrict__ pout,
                  const float* __restrict__ w, const float* __restrict__ bvec,
                  const int* __restrict__ knn, int npairs, int dout)
{
    const int lane = threadIdx.x & 63;
    const int r  = lane & 31;
    const int jj = lane >> 5;
    const int nw = gridDim.x << 2;
#pragma unroll 1
    for (int jp = (blockIdx.x << 2) + (threadIdx.x >> 6); jp < npairs; jp += nw) {
        const int j = (jp << 1) + jj;
        const int*   kn = knn + j * KNB;
        const float* ww = w   + j * KNB;
        float acc = bvec[j];
        GATHER25_T(acc, kn, ww, pin, r)
        pout[r * dout + j] = acc;   // row-major scatter (spread full-chip)
    }
}

// K4: layers 3-4 + FC, one block per row (32 x 1024).
__global__ __launch_bounds__(1024)
void tail34fc(const float* __restrict__ h3,
              const float* __restrict__ w3, const float* __restrict__ b3, const int* __restrict__ n3,
              const float* __restrict__ w4, const float* __restrict__ b4, const int* __restrict__ n4,
              const float* __restrict__ Wfc, const float* __restrict__ bfc,
              float* __restrict__ out)
{
    __shared__ float s3[D3];  // 7.2 KB
    __shared__ float s4[D4];  // 3.6 KB
    __shared__ float s5[D5];  // 1.8 KB
    __shared__ float red[2];

    const int r   = blockIdx.x;
    const int tid = threadIdx.x;

    if (tid < D3 / 4) {
        reinterpret_cast<float4*>(s3)[tid] =
            reinterpret_cast<const float4*>(h3 + (size_t)r * D3)[tid];
    }
    if (tid == 0) { red[0] = bfc[0]; red[1] = bfc[1]; }
    __syncthreads();

    // layer 3: 1800 -> 900
    if (tid < D4) {
        const int*   kn = n3 + tid * KNB;
        const float* ww = w3 + tid * KNB;
        float acc = b3[tid];
#define S3_SRC(idx) s3[idx]
        GATHER25(acc, kn, ww, S3_SRC)
#undef S3_SRC
        s4[tid] = acc;
    }
    __syncthreads();

    // layer 4: 900 -> 450
    if (tid < D5) {
        const int*   kn = n4 + tid * KNB;
        const float* ww = w4 + tid * KNB;
        float acc = b4[tid];
#define S4_SRC(idx) s4[idx]
        GATHER25(acc, kn, ww, S4_SRC)
#undef S4_SRC
        s5[tid] = acc;
    }
    __syncthreads();

    // FC: 450 -> 2
    float c0 = 0.0f, c1 = 0.0f;
    if (tid < D5) {
        const float v = s5[tid];
        c0 = v * Wfc[2 * tid + 0];
        c1 = v * Wfc[2 * tid + 1];
    }
#pragma unroll
    for (int off = 32; off > 0; off >>= 1) {
        c0 += __shfl_down(c0, off);
        c1 += __shfl_down(c1, off);
    }
    if ((tid & 63) == 0 && tid < D5) {
        atomicAdd(&red[0], c0);
        atomicAdd(&red[1], c1);
    }
    __syncthreads();
    if (tid < 2)
        out[2 * r + tid] = red[tid];
}

extern "C" void kernel_launch(void* const* d_in, const int* in_sizes, int n_in,
                              void* d_out, int out_size, void* d_ws, size_t ws_size,
                              hipStream_t stream)
{
    const float* x    = (const float*)d_in[0];
    const float* w0   = (const float*)d_in[1];
    const float* b0   = (const float*)d_in[2];
    const int*   knn0 = (const int*)  d_in[3];
    const float* w1   = (const float*)d_in[4];
    const float* b1   = (const float*)d_in[5];
    const int*   knn1 = (const int*)  d_in[6];
    const float* w2   = (const float*)d_in[7];
    const float* b2   = (const float*)d_in[8];
    const int*   knn2 = (const int*)  d_in[9];
    const float* w3   = (const float*)d_in[10];
    const float* b3   = (const float*)d_in[11];
    const int*   knn3 = (const int*)  d_in[12];
    const float* w4   = (const float*)d_in[13];
    const float* b4   = (const float*)d_in[14];
    const int*   knn4 = (const int*)  d_in[15];
    const float* Wfc  = (const float*)d_in[16];
    const float* bfc  = (const float*)d_in[17];
    float* out = (float*)d_out;

    // ws: h1t[D1][32] transposed | h2t[D2][32] transposed | h3[32][D3] row-major
    float* h1t = (float*)d_ws;
    float* h2t = h1t + (size_t)D1 * ROWS;
    float* h3  = h2t + (size_t)D2 * ROWS;

    // layer 0: x[:,T-1,:] -> h1t (transposed), 16 waves/CU
    l0_stage<<<dim3(D1 / 900, ROWS), dim3(1024), 0, stream>>>(x, h1t, w0, b0, knn0);

    // layer 1: h1t -> h2t (full chip, 1800 pairs, transposed write)
    layer_t_k<<<dim3(450), dim3(256), 0, stream>>>(h1t, h2t, w1, b1, knn1, D2 / 2);

    // layer 2: h2t -> h3 (full chip, 900 pairs, ROW-major write)
    layer_t_k_rm<<<dim3(225), dim3(256), 0, stream>>>(h2t, h3, w2, b2, knn2, D3 / 2, D3);

    // layers 3-4 + FC: one block per row, direct write (no memset)
    tail34fc<<<dim3(ROWS), dim3(1024), 0, stream>>>(
        h3,
        w3, b3, knn3,
        w4, b4, knn4,
        Wfc, bfc, out);
}

// Round 7
// 125.364 us; speedup vs baseline: 1.0212x; 1.0197x over previous
//
#include <hip/hip_runtime.h>

// LCN spiking net, round 12: r9 structure, l0 stage made async + 2 blocks/CU.
//  - r10/r11 lessons: extra nodes cost ~2us; widening one block doesn't add
//    concurrency (still 1 block/CU, all waves stall at the stage barrier).
//  - l0 fixes (only kernel changed vs the 126.1us r9 best):
//    (a) stage x row via __builtin_amdgcn_global_load_lds width=16: async
//        direct-to-LDS, no VGPR round-trip, all 15 iterations in flight,
//        single vmcnt(0) drain at the barrier.
//    (b) grid (16,32) = 512 blocks x 256 thr, 450 outputs each: 2x57.6KB
//        LDS = 115.2KB <= 160KB -> 2 independent blocks/CU; one block's
//        gather hides the other block's stage latency.
//  - l1 (transposed), l2 (row-major handoff), tail34fc: identical to r9.

#define ROWS 32
#define TSTEPS 20
#define D0 14400
#define D1 7200
#define D2 3600
#define D3 1800
#define D4 900
#define D5 450
#define KNB 25

typedef __attribute__((address_space(1))) const void gas_void;
typedef __attribute__((address_space(3))) void las_void;

// 25-element gather from an LDS row, 16B index/weight loads.
#define GATHER25(acc, kp, wp, SRC)                                  \
    {                                                               \
        _Pragma("unroll")                                           \
        for (int k = 0; k < 24; k += 4) {                           \
            int4   ki; __builtin_memcpy(&ki, (kp) + k, 16);         \
            float4 wi; __builtin_memcpy(&wi, (wp) + k, 16);         \
            acc += SRC(ki.x) * wi.x + SRC(ki.y) * wi.y              \
                 + SRC(ki.z) * wi.z + SRC(ki.w) * wi.w;             \
        }                                                           \
        acc += SRC((kp)[24]) * (wp)[24];                            \
    }

// 25-element transposed-layout gather: pin[(idx<<5)+r], 16B kn/w loads.
#define GATHER25_T(acc, kp, wp, pin, r)                             \
    {                                                               \
        _Pragma("unroll")                                           \
        for (int k = 0; k < 24; k += 4) {                           \
            int4   ki; __builtin_memcpy(&ki, (kp) + k, 16);         \
            float4 wi; __builtin_memcpy(&wi, (wp) + k, 16);         \
            acc += (pin)[(ki.x << 5) + (r)] * wi.x                  \
                 + (pin)[(ki.y << 5) + (r)] * wi.y                  \
                 + (pin)[(ki.z << 5) + (r)] * wi.z                  \
                 + (pin)[(ki.w << 5) + (r)] * wi.w;                 \
        }                                                           \
        acc += (pin)[((kp)[24] << 5) + (r)] * (wp)[24];             \
    }

// K1: layer 0. Grid (16, ROWS) = 512 blocks, 256 threads, 2 blocks/CU.
// Async global->LDS stage of the 57.6KB x row, then 450 outputs/block,
// write h1t transposed.
__global__ __launch_bounds__(256)
void l0_stage(const float* __restrict__ x, float* __restrict__ h1t,
              const float* __restrict__ w, const float* __restrict__ bvec,
              const int* __restrict__ knn)
{
    __shared__ float s[D0];   // 57.6 KB
    const int r = blockIdx.y;
    const int tid = threadIdx.x;
    const float* xrow = x + ((size_t)r * TSTEPS + (TSTEPS - 1)) * (size_t)D0;

    // async stage: 16B per lane per iter, LDS dst = wave-uniform base + lane*16
    {
        const float4* src = reinterpret_cast<const float4*>(xrow);
        float4* dst = reinterpret_cast<float4*>(s);
#pragma unroll 1
        for (int i = tid; i < D0 / 4; i += 256) {
            __builtin_amdgcn_global_load_lds((gas_void*)(src + i),
                                             (las_void*)(dst + (i & ~63)),
                                             16, 0, 0);
        }
    }
    __syncthreads();   // compiler emits vmcnt(0) drain before the barrier

    const int j0 = blockIdx.x * 450;
#pragma unroll 1
    for (int j = j0 + tid; j < j0 + 450; j += 256) {
        const int*   kn = knn + j * KNB;
        const float* ww = w   + j * KNB;
        float acc = bvec[j];
#define LDS_SRC(idx) s[idx]
        GATHER25(acc, kn, ww, LDS_SRC)
#undef LDS_SRC
        h1t[(j << 5) + r] = acc;   // transposed write
    }
}

// K2: transposed gather -> transposed write.
// pout[j][r] = b[j] + sum_k pin[knn[j][k]][r]*w[j][k]
// Wave = 2 outputs x 32 rows; gather = 1 contiguous 128B line per half-wave.
__global__ __launch_bounds__(256)
void layer_t_k(const float* __restrict__ pin, float* __restrict__ pout,
               const float* __restrict__ w, const float* __restrict__ bvec,
               const int* __restrict__ knn, int npairs)
{
    const int lane = threadIdx.x & 63;
    const int r  = lane & 31;
    const int jj = lane >> 5;
    const int nw = gridDim.x << 2;
#pragma unroll 1
    for (int jp = (blockIdx.x << 2) + (threadIdx.x >> 6); jp < npairs; jp += nw) {
        const int j = (jp << 1) + jj;
        const int*   kn = knn + j * KNB;
        const float* ww = w   + j * KNB;
        float acc = bvec[j];
        GATHER25_T(acc, kn, ww, pin, r)
        pout[(j << 5) + r] = acc;
    }
}

// K3: transposed gather -> ROW-major write (for the tail's coalesced stage).
__global__ __launch_bounds__(256)
void layer_t_k_rm(const float* __restrict__ pin, float* __restrict__ pout,
                  const float* __restrict__ w, const float* __restrict__ bvec,
                  const int* __restrict__ knn, int npairs, int dout)
{
    const int lane = threadIdx.x & 63;
    const int r  = lane & 31;
    const int jj = lane >> 5;
    const int nw = gridDim.x << 2;
#pragma unroll 1
    for (int jp = (blockIdx.x << 2) + (threadIdx.x >> 6); jp < npairs; jp += nw) {
        const int j = (jp << 1) + jj;
        const int*   kn = knn + j * KNB;
        const float* ww = w   + j * KNB;
        float acc = bvec[j];
        GATHER25_T(acc, kn, ww, pin, r)
        pout[r * dout + j] = acc;   // row-major scatter (spread full-chip)
    }
}

// K4: layers 3-4 + FC, one block per row (32 x 1024).
__global__ __launch_bounds__(1024)
void tail34fc(const float* __restrict__ h3,
              const float* __restrict__ w3, const float* __restrict__ b3, const int* __restrict__ n3,
              const float* __restrict__ w4, const float* __restrict__ b4, const int* __restrict__ n4,
              const float* __restrict__ Wfc, const float* __restrict__ bfc,
              float* __restrict__ out)
{
    __shared__ float s3[D3];  // 7.2 KB
    __shared__ float s4[D4];  // 3.6 KB
    __shared__ float s5[D5];  // 1.8 KB
    __shared__ float red[2];

    const int r   = blockIdx.x;
    const int tid = threadIdx.x;

    if (tid < D3 / 4) {
        reinterpret_cast<float4*>(s3)[tid] =
            reinterpret_cast<const float4*>(h3 + (size_t)r * D3)[tid];
    }
    if (tid == 0) { red[0] = bfc[0]; red[1] = bfc[1]; }
    __syncthreads();

    // layer 3: 1800 -> 900
    if (tid < D4) {
        const int*   kn = n3 + tid * KNB;
        const float* ww = w3 + tid * KNB;
        float acc = b3[tid];
#define S3_SRC(idx) s3[idx]
        GATHER25(acc, kn, ww, S3_SRC)
#undef S3_SRC
        s4[tid] = acc;
    }
    __syncthreads();

    // layer 4: 900 -> 450
    if (tid < D5) {
        const int*   kn = n4 + tid * KNB;
        const float* ww = w4 + tid * KNB;
        float acc = b4[tid];
#define S4_SRC(idx) s4[idx]
        GATHER25(acc, kn, ww, S4_SRC)
#undef S4_SRC
        s5[tid] = acc;
    }
    __syncthreads();

    // FC: 450 -> 2
    float c0 = 0.0f, c1 = 0.0f;
    if (tid < D5) {
        const float v = s5[tid];
        c0 = v * Wfc[2 * tid + 0];
        c1 = v * Wfc[2 * tid + 1];
    }
#pragma unroll
    for (int off = 32; off > 0; off >>= 1) {
        c0 += __shfl_down(c0, off);
        c1 += __shfl_down(c1, off);
    }
    if ((tid & 63) == 0 && tid < D5) {
        atomicAdd(&red[0], c0);
        atomicAdd(&red[1], c1);
    }
    __syncthreads();
    if (tid < 2)
        out[2 * r + tid] = red[tid];
}

extern "C" void kernel_launch(void* const* d_in, const int* in_sizes, int n_in,
                              void* d_out, int out_size, void* d_ws, size_t ws_size,
                              hipStream_t stream)
{
    const float* x    = (const float*)d_in[0];
    const float* w0   = (const float*)d_in[1];
    const float* b0   = (const float*)d_in[2];
    const int*   knn0 = (const int*)  d_in[3];
    const float* w1   = (const float*)d_in[4];
    const float* b1   = (const float*)d_in[5];
    const int*   knn1 = (const int*)  d_in[6];
    const float* w2   = (const float*)d_in[7];
    const float* b2   = (const float*)d_in[8];
    const int*   knn2 = (const int*)  d_in[9];
    const float* w3   = (const float*)d_in[10];
    const float* b3   = (const float*)d_in[11];
    const int*   knn3 = (const int*)  d_in[12];
    const float* w4   = (const float*)d_in[13];
    const float* b4   = (const float*)d_in[14];
    const int*   knn4 = (const int*)  d_in[15];
    const float* Wfc  = (const float*)d_in[16];
    const float* bfc  = (const float*)d_in[17];
    float* out = (float*)d_out;

    // ws: h1t[D1][32] transposed | h2t[D2][32] transposed | h3[32][D3] row-major
    float* h1t = (float*)d_ws;
    float* h2t = h1t + (size_t)D1 * ROWS;
    float* h3  = h2t + (size_t)D2 * ROWS;

    // layer 0: x[:,T-1,:] -> h1t (transposed), 512 blocks, 2 blocks/CU
    l0_stage<<<dim3(D0 / 900, ROWS), dim3(256), 0, stream>>>(x, h1t, w0, b0, knn0);

    // layer 1: h1t -> h2t (full chip, 1800 pairs, transposed write)
    layer_t_k<<<dim3(450), dim3(256), 0, stream>>>(h1t, h2t, w1, b1, knn1, D2 / 2);

    // layer 2: h2t -> h3 (full chip, 900 pairs, ROW-major write)
    layer_t_k_rm<<<dim3(225), dim3(256), 0, stream>>>(h2t, h3, w2, b2, knn2, D3 / 2, D3);

    // layers 3-4 + FC: one block per row, direct write (no memset)
    tail34fc<<<dim3(ROWS), dim3(1024), 0, stream>>>(
        h3,
        w3, b3, knn3,
        w4, b4, knn4,
        Wfc, bfc, out);
}